// Round 2
// baseline (684.312 us; speedup 1.0000x reference)
//
#include <hip/hip_runtime.h>
#include <hip/hip_fp16.h>
#include <cstdint>

// Problem constants: B=8, S=4096, D=1024, window +-128, out fp32.
// Pipeline: cvt x->fp16; cvt+transpose W->fp16; QKV MFMA GEMM (fp16 in, fp16 out,
// V in 8-inner [s/8][d][8] layout); banded QK^T+softmax -> P fp16 [tile64][320];
// banded PV -> fp32 out.
// Workspace layout (halves): xh[33554432] | wt[3*1048576] | qh[33554432] |
// kh[33554432] | v8[33554432]  (P[10485760] aliases xh, dead after GEMM1)
// total 274,726,912 bytes.

#define DEV __device__ __forceinline__

typedef _Float16 f16x8 __attribute__((ext_vector_type(8)));
typedef _Float16 f16x4 __attribute__((ext_vector_type(4)));
typedef float    f32x4 __attribute__((ext_vector_type(4)));

DEV _Float16 f2h(float f) { return (_Float16)f; }

DEV void gl16(const void* g, void* l) {
  __builtin_amdgcn_global_load_lds(
      (const __attribute__((address_space(1))) void*)(uintptr_t)g,
      (__attribute__((address_space(3))) void*)(uintptr_t)l, 16, 0, 0);
}

#define MFMA16(a, b, c) __builtin_amdgcn_mfma_f32_16x16x32_f16((a), (b), (c), 0, 0, 0)

// ---------------- convert x (fp32 -> fp16), 8 elems/thread ----------------
__global__ __launch_bounds__(256) void k_cvt_x(const float* __restrict__ x,
                                               _Float16* __restrict__ xh) {
  size_t i = ((size_t)blockIdx.x * 256 + threadIdx.x) * 8;
  float4 f0 = *(const float4*)(x + i);
  float4 f1 = *(const float4*)(x + i + 4);
  f16x8 o;
  o[0] = f2h(f0.x); o[1] = f2h(f0.y); o[2] = f2h(f0.z); o[3] = f2h(f0.w);
  o[4] = f2h(f1.x); o[5] = f2h(f1.y); o[6] = f2h(f1.z); o[7] = f2h(f1.w);
  *(f16x8*)(xh + i) = o;
}

// ------------- transpose+convert W [k][n] fp32 -> Wt [n][k] fp16 -------------
__global__ __launch_bounds__(256) void k_cvt_w(const float* __restrict__ Wq,
                                               const float* __restrict__ Wk,
                                               const float* __restrict__ Wv,
                                               _Float16* __restrict__ wt) {
  __shared__ float tile[64][65];
  const int z = blockIdx.z;
  const int n0 = blockIdx.x * 64, k0 = blockIdx.y * 64;
  const float* W = (z == 0) ? Wq : (z == 1) ? Wk : Wv;
  const int tid = threadIdx.x;
  const int r0 = tid >> 4;           // 0..15
  const int c4 = (tid & 15) * 4;     // 0..60
#pragma unroll
  for (int rr = 0; rr < 4; ++rr) {
    int r = r0 + rr * 16;
    float4 v = *(const float4*)(W + (size_t)(k0 + r) * 1024 + n0 + c4);
    tile[r][c4 + 0] = v.x; tile[r][c4 + 1] = v.y;
    tile[r][c4 + 2] = v.z; tile[r][c4 + 3] = v.w;
  }
  __syncthreads();
  _Float16* out = wt + (size_t)z * 1048576;
#pragma unroll
  for (int rr = 0; rr < 4; ++rr) {
    int n = r0 + rr * 16;
    f16x4 o;
#pragma unroll
    for (int jj = 0; jj < 4; ++jj) o[jj] = f2h(tile[c4 + jj][n]);
    *(f16x4*)(out + (size_t)(n0 + n) * 1024 + k0 + c4) = o;
  }
}

// ---------------- QKV GEMM: [32768x1024] x Wt^T, 128x128 tile ----------------
__global__ __launch_bounds__(256) void k_gemm_qkv(
    const _Float16* __restrict__ xh, const _Float16* __restrict__ wt,
    const float* __restrict__ bq, const float* __restrict__ bk,
    const float* __restrict__ bv, _Float16* __restrict__ qh,
    _Float16* __restrict__ kh, _Float16* __restrict__ v8) {
  __shared__ _Float16 lA[128 * 64];
  __shared__ _Float16 lB[128 * 64];
  const int z = blockIdx.z;
  const _Float16* Bm = wt + (size_t)z * 1048576;
  const float* bias = (z == 0) ? bq : (z == 1) ? bk : bv;
  const int gm0 = blockIdx.y * 128, gn0 = blockIdx.x * 128;
  const int tid = threadIdx.x, w = tid >> 6, l = tid & 63;
  const int ln = l & 15, quad = l >> 4;
  const int rb = (w >> 1) * 64, cb = (w & 1) * 64;

  f32x4 acc[4][4] = {};

  for (int it = 0; it < 16; ++it) {
#pragma unroll
    for (int c = 0; c < 4; ++c) {
      int cid = w * 4 + c;
      int rl = cid * 8 + (l >> 3);
      int kc = (l & 7) * 8;
      gl16(xh + (size_t)(gm0 + rl) * 1024 + it * 64 + kc, lA + cid * 512);
      gl16(Bm + (size_t)(gn0 + rl) * 1024 + it * 64 + kc, lB + cid * 512);
    }
    __builtin_amdgcn_s_waitcnt(0);
    __syncthreads();
#pragma unroll
    for (int kk = 0; kk < 64; kk += 32) {
      f16x8 af[4], bf[4];
#pragma unroll
      for (int i = 0; i < 4; ++i)
        af[i] = *(const f16x8*)(lA + (rb + i * 16 + ln) * 64 + kk + quad * 8);
#pragma unroll
      for (int j = 0; j < 4; ++j)
        bf[j] = *(const f16x8*)(lB + (cb + j * 16 + ln) * 64 + kk + quad * 8);
#pragma unroll
      for (int i = 0; i < 4; ++i)
#pragma unroll
        for (int j = 0; j < 4; ++j)
          acc[i][j] = MFMA16(af[i], bf[j], acc[i][j]);
    }
    __syncthreads();
  }

  const int col0 = gn0 + cb;
  if (z != 2) {
    _Float16* outp = (z == 0) ? qh : kh;
#pragma unroll
    for (int j = 0; j < 4; ++j) {
      float bb = bias[col0 + j * 16 + ln];
#pragma unroll
      for (int i = 0; i < 4; ++i) {
        int row = gm0 + rb + i * 16 + quad * 4;
        size_t base = (size_t)row * 1024 + col0 + j * 16 + ln;
#pragma unroll
        for (int r = 0; r < 4; ++r)
          outp[base + (size_t)r * 1024] = f2h(acc[i][j][r] + bb);
      }
    }
  } else {
    // V in 8-inner layout: v8[(row/8)*8192 + col*8 + row%8]
#pragma unroll
    for (int j = 0; j < 4; ++j) {
      float bb = bias[col0 + j * 16 + ln];
#pragma unroll
      for (int i = 0; i < 4; ++i) {
        int row0 = gm0 + rb + i * 16 + quad * 4;  // 4 consecutive rows
        int col = col0 + j * 16 + ln;
        f16x4 o;
#pragma unroll
        for (int r = 0; r < 4; ++r) o[r] = f2h(acc[i][j][r] + bb);
        *(f16x4*)(v8 + (size_t)(row0 >> 3) * 8192 + (size_t)col * 8 + (row0 & 7)) = o;
      }
    }
  }
}

// -------- banded scores + softmax: per (tile of 64 q, batch) -> P fp16 --------
__global__ __launch_bounds__(256) void k_scores(const _Float16* __restrict__ qh,
                                                const _Float16* __restrict__ kh,
                                                _Float16* __restrict__ ph) {
  __shared__ _Float16 lQ[64 * 64];
  __shared__ _Float16 lK[320 * 64];
  const int t = blockIdx.x, b = blockIdx.y;
  const int i0 = t * 64, k0 = i0 - 128;
  const int tid = threadIdx.x, w = tid >> 6, l = tid & 63;
  const int ln = l & 15, quad = l >> 4;
  const _Float16* qrow = qh + (size_t)b * 4096 * 1024;
  const _Float16* krow = kh + (size_t)b * 4096 * 1024;

  f32x4 acc[20] = {};

  for (int it = 0; it < 16; ++it) {
#pragma unroll
    for (int c = 0; c < 2; ++c) {
      int cid = w * 2 + c;
      int rl = cid * 8 + (l >> 3);
      int kc = (l & 7) * 8;
      gl16(qrow + (size_t)(i0 + rl) * 1024 + it * 64 + kc, lQ + cid * 512);
    }
#pragma unroll
    for (int c = 0; c < 10; ++c) {
      int cid = w * 10 + c;
      int rl = cid * 8 + (l >> 3);
      int kc = (l & 7) * 8;
      int gr = k0 + rl;
      gr = min(max(gr, 0), 4095);  // clamped rows are masked below
      gl16(krow + (size_t)gr * 1024 + it * 64 + kc, lK + cid * 512);
    }
    __builtin_amdgcn_s_waitcnt(0);
    __syncthreads();
#pragma unroll
    for (int kk = 0; kk < 64; kk += 32) {
      f16x8 a = *(const f16x8*)(lQ + (w * 16 + ln) * 64 + kk + quad * 8);
#pragma unroll
      for (int j = 0; j < 20; ++j) {
        f16x8 bf = *(const f16x8*)(lK + (j * 16 + ln) * 64 + kk + quad * 8);
        acc[j] = MFMA16(a, bf, acc[j]);
      }
    }
    __syncthreads();
  }

  // mask + softmax (C-layout: col=j*16+ln, row=w*16+quad*4+r)
  const float scale = 0.03125f;  // 1/sqrt(1024)
  float mrow[4] = {-1e30f, -1e30f, -1e30f, -1e30f};
#pragma unroll
  for (int j = 0; j < 20; ++j) {
    int jc = k0 + j * 16 + ln;
    bool cval = (jc >= 0) && (jc < 4096);
#pragma unroll
    for (int r = 0; r < 4; ++r) {
      int i = i0 + w * 16 + quad * 4 + r;
      int rel = jc - i;
      bool val = cval && (rel >= -128) && (rel <= 128);
      float s = val ? acc[j][r] * scale : -1e30f;
      acc[j][r] = s;
      mrow[r] = fmaxf(mrow[r], s);
    }
  }
#pragma unroll
  for (int r = 0; r < 4; ++r)
#pragma unroll
    for (int m = 1; m < 16; m <<= 1) mrow[r] = fmaxf(mrow[r], __shfl_xor(mrow[r], m));
  float sum[4] = {0.f, 0.f, 0.f, 0.f};
#pragma unroll
  for (int j = 0; j < 20; ++j)
#pragma unroll
    for (int r = 0; r < 4; ++r) {
      float e = __builtin_exp2f((acc[j][r] - mrow[r]) * 1.44269504f);
      acc[j][r] = e;
      sum[r] += e;
    }
#pragma unroll
  for (int r = 0; r < 4; ++r) {
#pragma unroll
    for (int m = 1; m < 16; m <<= 1) sum[r] += __shfl_xor(sum[r], m);
    sum[r] = 1.0f / sum[r];
  }
  _Float16* pt = ph + (size_t)(b * 64 + t) * 64 * 320;
#pragma unroll
  for (int j = 0; j < 20; ++j)
#pragma unroll
    for (int r = 0; r < 4; ++r)
      pt[(size_t)(w * 16 + quad * 4 + r) * 320 + j * 16 + ln] = f2h(acc[j][r] * sum[r]);
}

// ---------------- PV: out[64 x 256] = P[64 x 320] * V[320 x 256] ----------------
__global__ __launch_bounds__(256) void k_pv(const _Float16* __restrict__ ph,
                                            const _Float16* __restrict__ v8,
                                            float* __restrict__ out) {
  __shared__ _Float16 lP[64 * 40];      // rows padded 32 -> 40 (bank spread)
  __shared__ _Float16 lV[4 * 256 * 8];  // [k-octet][n][8]
  const int nc = blockIdx.x, t = blockIdx.y, b = blockIdx.z;
  const int n0 = nc * 256;
  const int tid = threadIdx.x, w = tid >> 6, l = tid & 63;
  const int ln = l & 15, quad = l >> 4;
  const _Float16* pt = ph + (size_t)(b * 64 + t) * 64 * 320;
  const _Float16* vb = v8 + (size_t)b * 4194304;
  const int k0 = t * 64 - 128;

  f32x4 acc[16] = {};

  for (int it = 0; it < 10; ++it) {
    int kk = it * 32;
    if (it) __syncthreads();
    {  // stage P tile [64][32]: 256 threads x 8 halves = 2048 halves (full tile)
      int row = tid >> 2, ch = tid & 3;
      f16x8 d = *(const f16x8*)(pt + (size_t)row * 320 + kk + ch * 8);
      *(f16x8*)(lP + row * 40 + ch * 8) = d;
    }
#pragma unroll
    for (int c = 0; c < 4; ++c) {  // stage V [4 octets][256 n][8]
      int nloc = w * 64 + l;
      int g = ((k0 + kk) >> 3) + c;
      g = min(max(g, 0), 511);  // P==0 on clamped keys
      gl16(vb + (size_t)g * 8192 + (size_t)(n0 + nloc) * 8, lV + (c * 256 + w * 64) * 8);
    }
    __builtin_amdgcn_s_waitcnt(0);
    __syncthreads();
    f16x8 a = *(const f16x8*)(lP + (w * 16 + ln) * 40 + quad * 8);
#pragma unroll
    for (int j = 0; j < 16; ++j) {
      f16x8 bv = *(const f16x8*)(lV + (quad * 256 + j * 16 + ln) * 8);
      acc[j] = MFMA16(a, bv, acc[j]);
    }
  }

#pragma unroll
  for (int j = 0; j < 16; ++j) {
    int col = n0 + j * 16 + ln;
    int row = t * 64 + w * 16 + quad * 4;
    size_t base = ((size_t)b * 4096 + row) * 1024 + col;
#pragma unroll
    for (int r = 0; r < 4; ++r) out[base + (size_t)r * 1024] = acc[j][r];
  }
}

extern "C" void kernel_launch(void* const* d_in, const int* in_sizes, int n_in,
                              void* d_out, int out_size, void* d_ws, size_t ws_size,
                              hipStream_t stream) {
  const float* x  = (const float*)d_in[0];
  const float* Wq = (const float*)d_in[1];
  const float* bq = (const float*)d_in[2];
  const float* Wk = (const float*)d_in[3];
  const float* bk = (const float*)d_in[4];
  const float* Wv = (const float*)d_in[5];
  const float* bv = (const float*)d_in[6];
  float* out = (float*)d_out;

  _Float16* ws = (_Float16*)d_ws;
  _Float16* xh = ws;                    // 33554432
  _Float16* wt = ws + 33554432;         // 3145728
  _Float16* qh = ws + 36700160;         // 33554432
  _Float16* kh = ws + 70254592;         // 33554432
  _Float16* v8 = ws + 103809024;        // 33554432
  _Float16* ph = ws;                    // aliases xh (dead after GEMM1); 10485760

  k_cvt_x<<<16384, 256, 0, stream>>>(x, xh);
  k_cvt_w<<<dim3(16, 16, 3), 256, 0, stream>>>(Wq, Wk, Wv, wt);
  k_gemm_qkv<<<dim3(8, 256, 3), 256, 0, stream>>>(xh, wt, bq, bk, bv, qh, kh, v8);
  k_scores<<<dim3(64, 8), 256, 0, stream>>>(qh, kh, ph);
  k_pv<<<dim3(4, 64, 8), 256, 0, stream>>>(ph, v8, out);
}

// Round 3
// 670.749 us; speedup vs baseline: 1.0202x; 1.0202x over previous
//
#include <hip/hip_runtime.h>
#include <hip/hip_fp16.h>
#include <cstdint>

// B=8, S=4096, D=1024, window +-128, out fp32.
// Pipeline: cvt x->fp16; cvt+transpose W->fp16; QKV MFMA GEMM; banded
// QK^T+softmax -> P fp16; banded PV -> fp32 out.
// LDS tiles use XOR-octet swizzle (physical octet = logical ^ (row&7)) to kill
// the 16-way ds_read_b128 bank conflict of a 128B row stride (R2: 7.55e7
// SQ_LDS_BANK_CONFLICT, gemm at 597 TF DS-pipe-bound).
// Workspace (halves): xh[33554432] | wt[3*1048576] | qh[33554432] |
// kh[33554432] | v8[33554432]  (P aliases xh, dead after GEMM1)

#define DEV __device__ __forceinline__

typedef _Float16 f16x8 __attribute__((ext_vector_type(8)));
typedef _Float16 f16x4 __attribute__((ext_vector_type(4)));
typedef float    f32x4 __attribute__((ext_vector_type(4)));

DEV _Float16 f2h(float f) { return (_Float16)f; }

DEV void gl16(const void* g, void* l) {
  __builtin_amdgcn_global_load_lds(
      (const __attribute__((address_space(1))) void*)(uintptr_t)g,
      (__attribute__((address_space(3))) void*)(uintptr_t)l, 16, 0, 0);
}

#define MFMA16(a, b, c) __builtin_amdgcn_mfma_f32_16x16x32_f16((a), (b), (c), 0, 0, 0)

// ---------------- convert x (fp32 -> fp16), 8 elems/thread ----------------
__global__ __launch_bounds__(256) void k_cvt_x(const float* __restrict__ x,
                                               _Float16* __restrict__ xh) {
  size_t i = ((size_t)blockIdx.x * 256 + threadIdx.x) * 8;
  float4 f0 = *(const float4*)(x + i);
  float4 f1 = *(const float4*)(x + i + 4);
  f16x8 o;
  o[0] = f2h(f0.x); o[1] = f2h(f0.y); o[2] = f2h(f0.z); o[3] = f2h(f0.w);
  o[4] = f2h(f1.x); o[5] = f2h(f1.y); o[6] = f2h(f1.z); o[7] = f2h(f1.w);
  *(f16x8*)(xh + i) = o;
}

// ------------- transpose+convert W [k][n] fp32 -> Wt [n][k] fp16 -------------
__global__ __launch_bounds__(256) void k_cvt_w(const float* __restrict__ Wq,
                                               const float* __restrict__ Wk,
                                               const float* __restrict__ Wv,
                                               _Float16* __restrict__ wt) {
  __shared__ float tile[64][65];
  const int z = blockIdx.z;
  const int n0 = blockIdx.x * 64, k0 = blockIdx.y * 64;
  const float* W = (z == 0) ? Wq : (z == 1) ? Wk : Wv;
  const int tid = threadIdx.x;
  const int r0 = tid >> 4;           // 0..15
  const int c4 = (tid & 15) * 4;     // 0..60
#pragma unroll
  for (int rr = 0; rr < 4; ++rr) {
    int r = r0 + rr * 16;
    float4 v = *(const float4*)(W + (size_t)(k0 + r) * 1024 + n0 + c4);
    tile[r][c4 + 0] = v.x; tile[r][c4 + 1] = v.y;
    tile[r][c4 + 2] = v.z; tile[r][c4 + 3] = v.w;
  }
  __syncthreads();
  _Float16* out = wt + (size_t)z * 1048576;
#pragma unroll
  for (int rr = 0; rr < 4; ++rr) {
    int n = r0 + rr * 16;
    f16x4 o;
#pragma unroll
    for (int jj = 0; jj < 4; ++jj) o[jj] = f2h(tile[c4 + jj][n]);
    *(f16x4*)(out + (size_t)(n0 + n) * 1024 + k0 + c4) = o;
  }
}

// ---------------- QKV GEMM: [32768x1024] x Wt^T, 128x128 tile ----------------
__global__ __launch_bounds__(256) void k_gemm_qkv(
    const _Float16* __restrict__ xh, const _Float16* __restrict__ wt,
    const float* __restrict__ bq, const float* __restrict__ bk,
    const float* __restrict__ bv, _Float16* __restrict__ qh,
    _Float16* __restrict__ kh, _Float16* __restrict__ v8) {
  __shared__ _Float16 lA[128 * 64];
  __shared__ _Float16 lB[128 * 64];
  const int z = blockIdx.z;
  const _Float16* Bm = wt + (size_t)z * 1048576;
  const float* bias = (z == 0) ? bq : (z == 1) ? bk : bv;
  const int gm0 = blockIdx.y * 128, gn0 = blockIdx.x * 128;
  const int tid = threadIdx.x, w = tid >> 6, l = tid & 63;
  const int ln = l & 15, quad = l >> 4;
  const int rb = (w >> 1) * 64, cb = (w & 1) * 64;
  // staging source column: physical octet (l&7) holds logical octet (l&7)^(l>>3)
  const int kc = (((l & 7) ^ (l >> 3)) * 8);
  const int swz = ln & 7;  // fragment-read octet xor (row&7 == ln&7)

  f32x4 acc[4][4] = {};

  for (int it = 0; it < 16; ++it) {
#pragma unroll
    for (int c = 0; c < 4; ++c) {
      int cid = w * 4 + c;
      int rl = cid * 8 + (l >> 3);
      gl16(xh + (size_t)(gm0 + rl) * 1024 + it * 64 + kc, lA + cid * 512);
      gl16(Bm + (size_t)(gn0 + rl) * 1024 + it * 64 + kc, lB + cid * 512);
    }
    __builtin_amdgcn_s_waitcnt(0);
    __syncthreads();
#pragma unroll
    for (int kk = 0; kk < 64; kk += 32) {
      f16x8 af[4], bf[4];
#pragma unroll
      for (int i = 0; i < 4; ++i)
        af[i] = *(const f16x8*)(lA + (rb + i * 16 + ln) * 64 +
                                (((kk >> 3) + quad) ^ swz) * 8);
#pragma unroll
      for (int j = 0; j < 4; ++j)
        bf[j] = *(const f16x8*)(lB + (cb + j * 16 + ln) * 64 +
                                (((kk >> 3) + quad) ^ swz) * 8);
#pragma unroll
      for (int i = 0; i < 4; ++i)
#pragma unroll
        for (int j = 0; j < 4; ++j)
          acc[i][j] = MFMA16(af[i], bf[j], acc[i][j]);
    }
    __syncthreads();
  }

  const int col0 = gn0 + cb;
  if (z != 2) {
    _Float16* outp = (z == 0) ? qh : kh;
#pragma unroll
    for (int j = 0; j < 4; ++j) {
      float bb = bias[col0 + j * 16 + ln];
#pragma unroll
      for (int i = 0; i < 4; ++i) {
        int row = gm0 + rb + i * 16 + quad * 4;
        size_t base = (size_t)row * 1024 + col0 + j * 16 + ln;
#pragma unroll
        for (int r = 0; r < 4; ++r)
          outp[base + (size_t)r * 1024] = f2h(acc[i][j][r] + bb);
      }
    }
  } else {
    // V in 8-inner layout: v8[(row/8)*8192 + col*8 + row%8]
#pragma unroll
    for (int j = 0; j < 4; ++j) {
      float bb = bias[col0 + j * 16 + ln];
#pragma unroll
      for (int i = 0; i < 4; ++i) {
        int row0 = gm0 + rb + i * 16 + quad * 4;  // 4 consecutive rows
        int col = col0 + j * 16 + ln;
        f16x4 o;
#pragma unroll
        for (int r = 0; r < 4; ++r) o[r] = f2h(acc[i][j][r] + bb);
        *(f16x4*)(v8 + (size_t)(row0 >> 3) * 8192 + (size_t)col * 8 + (row0 & 7)) = o;
      }
    }
  }
}

// -------- banded scores + softmax: per (tile of 64 q, batch) -> P fp16 --------
__global__ __launch_bounds__(256) void k_scores(const _Float16* __restrict__ qh,
                                                const _Float16* __restrict__ kh,
                                                _Float16* __restrict__ ph) {
  __shared__ _Float16 lQ[64 * 64];
  __shared__ _Float16 lK[320 * 64];
  const int t = blockIdx.x, b = blockIdx.y;
  const int i0 = t * 64, k0 = i0 - 128;
  const int tid = threadIdx.x, w = tid >> 6, l = tid & 63;
  const int ln = l & 15, quad = l >> 4;
  const _Float16* qrow = qh + (size_t)b * 4096 * 1024;
  const _Float16* krow = kh + (size_t)b * 4096 * 1024;
  const int kc = (((l & 7) ^ (l >> 3)) * 8);
  const int swz = ln & 7;

  f32x4 acc[20] = {};

  for (int it = 0; it < 16; ++it) {
#pragma unroll
    for (int c = 0; c < 2; ++c) {
      int cid = w * 2 + c;
      int rl = cid * 8 + (l >> 3);
      gl16(qrow + (size_t)(i0 + rl) * 1024 + it * 64 + kc, lQ + cid * 512);
    }
#pragma unroll
    for (int c = 0; c < 10; ++c) {
      int cid = w * 10 + c;
      int rl = cid * 8 + (l >> 3);
      int gr = k0 + rl;
      gr = min(max(gr, 0), 4095);  // clamped rows are masked below
      gl16(krow + (size_t)gr * 1024 + it * 64 + kc, lK + cid * 512);
    }
    __builtin_amdgcn_s_waitcnt(0);
    __syncthreads();
#pragma unroll
    for (int kk = 0; kk < 64; kk += 32) {
      f16x8 a = *(const f16x8*)(lQ + (w * 16 + ln) * 64 +
                                (((kk >> 3) + quad) ^ swz) * 8);
#pragma unroll
      for (int j = 0; j < 20; ++j) {
        f16x8 bf = *(const f16x8*)(lK + (j * 16 + ln) * 64 +
                                   (((kk >> 3) + quad) ^ swz) * 8);
        acc[j] = MFMA16(a, bf, acc[j]);
      }
    }
    __syncthreads();
  }

  // mask + softmax (C-layout: col=j*16+ln, row=w*16+quad*4+r)
  const float scale = 0.03125f;  // 1/sqrt(1024)
  float mrow[4] = {-1e30f, -1e30f, -1e30f, -1e30f};
#pragma unroll
  for (int j = 0; j < 20; ++j) {
    int jc = k0 + j * 16 + ln;
    bool cval = (jc >= 0) && (jc < 4096);
#pragma unroll
    for (int r = 0; r < 4; ++r) {
      int i = i0 + w * 16 + quad * 4 + r;
      int rel = jc - i;
      bool val = cval && (rel >= -128) && (rel <= 128);
      float s = val ? acc[j][r] * scale : -1e30f;
      acc[j][r] = s;
      mrow[r] = fmaxf(mrow[r], s);
    }
  }
#pragma unroll
  for (int r = 0; r < 4; ++r)
#pragma unroll
    for (int m = 1; m < 16; m <<= 1) mrow[r] = fmaxf(mrow[r], __shfl_xor(mrow[r], m));
  float sum[4] = {0.f, 0.f, 0.f, 0.f};
#pragma unroll
  for (int j = 0; j < 20; ++j)
#pragma unroll
    for (int r = 0; r < 4; ++r) {
      float e = __builtin_exp2f((acc[j][r] - mrow[r]) * 1.44269504f);
      acc[j][r] = e;
      sum[r] += e;
    }
#pragma unroll
  for (int r = 0; r < 4; ++r) {
#pragma unroll
    for (int m = 1; m < 16; m <<= 1) sum[r] += __shfl_xor(sum[r], m);
    sum[r] = 1.0f / sum[r];
  }
  _Float16* pt = ph + (size_t)(b * 64 + t) * 64 * 320;
#pragma unroll
  for (int j = 0; j < 20; ++j)
#pragma unroll
    for (int r = 0; r < 4; ++r)
      pt[(size_t)(w * 16 + quad * 4 + r) * 320 + j * 16 + ln] = f2h(acc[j][r] * sum[r]);
}

// ---------------- PV: out[64 x 256] = P[64 x 320] * V[320 x 256] ----------------
__global__ __launch_bounds__(256) void k_pv(const _Float16* __restrict__ ph,
                                            const _Float16* __restrict__ v8,
                                            float* __restrict__ out) {
  __shared__ _Float16 lP[64 * 40];      // rows padded 32 -> 40 (bank spread)
  __shared__ _Float16 lV[4 * 256 * 8];  // [k-octet][n][8]
  const int nc = blockIdx.x, t = blockIdx.y, b = blockIdx.z;
  const int n0 = nc * 256;
  const int tid = threadIdx.x, w = tid >> 6, l = tid & 63;
  const int ln = l & 15, quad = l >> 4;
  const _Float16* pt = ph + (size_t)(b * 64 + t) * 64 * 320;
  const _Float16* vb = v8 + (size_t)b * 4194304;
  const int k0 = t * 64 - 128;

  f32x4 acc[16] = {};

  for (int it = 0; it < 10; ++it) {
    int kk = it * 32;
    if (it) __syncthreads();
    {  // stage P tile [64][32]: 256 threads x 8 halves = 2048 halves (full tile)
      int row = tid >> 2, ch = tid & 3;
      f16x8 d = *(const f16x8*)(pt + (size_t)row * 320 + kk + ch * 8);
      *(f16x8*)(lP + row * 40 + ch * 8) = d;
    }
#pragma unroll
    for (int c = 0; c < 4; ++c) {  // stage V [4 octets][256 n][8]
      int nloc = w * 64 + l;
      int g = ((k0 + kk) >> 3) + c;
      g = min(max(g, 0), 511);  // P==0 on clamped keys
      gl16(vb + (size_t)g * 8192 + (size_t)(n0 + nloc) * 8, lV + (c * 256 + w * 64) * 8);
    }
    __builtin_amdgcn_s_waitcnt(0);
    __syncthreads();
    f16x8 a = *(const f16x8*)(lP + (w * 16 + ln) * 40 + quad * 8);
#pragma unroll
    for (int j = 0; j < 16; ++j) {
      f16x8 bv = *(const f16x8*)(lV + (quad * 256 + j * 16 + ln) * 8);
      acc[j] = MFMA16(a, bv, acc[j]);
    }
  }

#pragma unroll
  for (int j = 0; j < 16; ++j) {
    int col = n0 + j * 16 + ln;
    int row = t * 64 + w * 16 + quad * 4;
    size_t base = ((size_t)b * 4096 + row) * 1024 + col;
#pragma unroll
    for (int r = 0; r < 4; ++r) out[base + (size_t)r * 1024] = acc[j][r];
  }
}

extern "C" void kernel_launch(void* const* d_in, const int* in_sizes, int n_in,
                              void* d_out, int out_size, void* d_ws, size_t ws_size,
                              hipStream_t stream) {
  const float* x  = (const float*)d_in[0];
  const float* Wq = (const float*)d_in[1];
  const float* bq = (const float*)d_in[2];
  const float* Wk = (const float*)d_in[3];
  const float* bk = (const float*)d_in[4];
  const float* Wv = (const float*)d_in[5];
  const float* bv = (const float*)d_in[6];
  float* out = (float*)d_out;

  _Float16* ws = (_Float16*)d_ws;
  _Float16* xh = ws;                    // 33554432
  _Float16* wt = ws + 33554432;         // 3145728
  _Float16* qh = ws + 36700160;         // 33554432
  _Float16* kh = ws + 70254592;         // 33554432
  _Float16* v8 = ws + 103809024;        // 33554432
  _Float16* ph = ws;                    // aliases xh (dead after GEMM1); 10485760

  k_cvt_x<<<16384, 256, 0, stream>>>(x, xh);
  k_cvt_w<<<dim3(16, 16, 3), 256, 0, stream>>>(Wq, Wk, Wv, wt);
  k_gemm_qkv<<<dim3(8, 256, 3), 256, 0, stream>>>(xh, wt, bq, bk, bv, qh, kh, v8);
  k_scores<<<dim3(64, 8), 256, 0, stream>>>(qh, kh, ph);
  k_pv<<<dim3(4, 64, 8), 256, 0, stream>>>(ph, v8, out);
}